// Round 1
// 999.495 us; speedup vs baseline: 1.0450x; 1.0450x over previous
//
#include <hip/hip_runtime.h>
#include <math.h>

typedef unsigned short ushort_t;
typedef unsigned int uint_t;

// Problem constants (fixed by the reference)
#define BB 16
#define TT 2000
#define DENC 512
#define VV 1024
#define EE 256
#define PP 640
#define MM (BB * TT)   // 32000 rows

// MFMA fragment types (per cdna_hip_programming.md §3, compile-verified on gfx950)
typedef __attribute__((ext_vector_type(8))) short bf16x8;
typedef __attribute__((ext_vector_type(4))) float f32x4;

// ---------------------------------------------------------------------------
// helpers
// ---------------------------------------------------------------------------
__device__ __forceinline__ ushort_t f2bf(float x) {
    union { float f; uint_t u; } v; v.f = x;
    uint_t r = v.u + 0x7fffu + ((v.u >> 16) & 1u);   // RTNE
    return (ushort_t)(r >> 16);
}

__device__ __forceinline__ void async_ld16(const ushort_t* g, ushort_t* l) {
    __builtin_amdgcn_global_load_lds(
        (const __attribute__((address_space(1))) void*)g,
        (__attribute__((address_space(3))) void*)l, 16, 0, 0);
}

// ---------------------------------------------------------------------------
// 1) Viterbi context: c[0]=0; c[t] = targets[t-1]!=0 ? targets[t-1] : c[t-1]
// ---------------------------------------------------------------------------
__global__ void ctx_kernel(const int* __restrict__ targets,
                           int* __restrict__ ctx0, int* __restrict__ ctx1) {
    __shared__ int tg[TT];
    __shared__ int cc[TT];
    const int b = blockIdx.x;
    const int* row = targets + b * TT;
    for (int t = threadIdx.x; t < TT; t += blockDim.x) tg[t] = row[t];
    __syncthreads();
    if (threadIdx.x == 0) {
        int cur = 0;
        for (int t = 0; t < TT; ++t) {
            cc[t] = cur;
            int v = tg[t];
            cur = (v != 0) ? v : cur;
        }
    }
    __syncthreads();
    for (int t = threadIdx.x; t < TT; t += blockDim.x) {
        ctx0[b * TT + t] = cc[t];
        ctx1[b * TT + t] = (t >= 1) ? cc[t - 1] : 0;
    }
}

// ---------------------------------------------------------------------------
// 2) Weight transpose + fp32->bf16: W[K,N] -> WT[N,K] (bf16)
// ---------------------------------------------------------------------------
__global__ __launch_bounds__(256) void transpose_cvt_kernel(
    const float* __restrict__ W, ushort_t* __restrict__ WT, int K, int N) {
    __shared__ float t[32][33];
    const int n0 = blockIdx.x * 32, k0 = blockIdx.y * 32;
    const int tx = threadIdx.x, ty0 = threadIdx.y;  // blockDim (32,8)
    #pragma unroll
    for (int i = 0; i < 4; ++i) {
        int ty = ty0 + i * 8;
        t[ty][tx] = W[(size_t)(k0 + ty) * N + n0 + tx];
    }
    __syncthreads();
    #pragma unroll
    for (int i = 0; i < 4; ++i) {
        int ty = ty0 + i * 8;
        WT[(size_t)(n0 + ty) * K + k0 + tx] = f2bf(t[tx][ty]);
    }
}

// ---------------------------------------------------------------------------
// 3) fp32 -> bf16 elementwise (n % 4 == 0)
// ---------------------------------------------------------------------------
__global__ __launch_bounds__(256) void cvt_kernel(const float* __restrict__ in,
                                                  ushort_t* __restrict__ out, int n) {
    int i = (blockIdx.x * 256 + threadIdx.x) * 4;
    if (i >= n) return;
    float4 v = *(const float4*)(in + i);
    ushort_t o[4] = {f2bf(v.x), f2bf(v.y), f2bf(v.z), f2bf(v.w)};
    *(uint2*)(out + i) = *(uint2*)o;
}

// ---------------------------------------------------------------------------
// 4) gather predictor input: out[m, 0:256]=emb[ctx0[m]], out[m,256:512]=emb[ctx1[m]]
//    128 threads: lane group 0..63 -> ctx0 row, 64..127 -> ctx1 row, float4 each
// ---------------------------------------------------------------------------
__global__ __launch_bounds__(128) void gather_kernel(const float* __restrict__ emb,
                                                     const int* __restrict__ ctx0,
                                                     const int* __restrict__ ctx1,
                                                     ushort_t* __restrict__ out) {
    const int m = blockIdx.x;
    const int t = threadIdx.x;           // 0..127
    const int half = t >> 6;             // 0: ctx0, 1: ctx1
    const int c = half ? ctx1[m] : ctx0[m];
    const int e = (t & 63) * 4;
    float4 v = *(const float4*)&emb[(size_t)c * EE + e];
    ushort_t o[4] = {f2bf(v.x), f2bf(v.y), f2bf(v.z), f2bf(v.w)};
    *(uint2*)&out[(size_t)m * 512 + half * 256 + e] = *(uint2*)o;
}

// ---------------------------------------------------------------------------
// 5) bf16 MFMA GEMM (m97 structure) + XCD-chunk swizzle:
//    C = act(A @ BT^T + bias); optional fused sum-output (SUM):
//      Cout fp32 = v;  sumOut bf16 = v + addIn   (joint-input fusion)
//    A [M,K] bf16 row-major, BT [N,K] bf16 row-major (pre-transposed weight)
//    128x128 tile, BK=32, 256 threads = 4 waves (2x2), 4x4 16x16x32 frags/wave
//    Launched as 1-D grid of GX*(M/128) blocks; bijective m204 chunk transform
//    so all GX col-blocks of a row-panel land on ONE XCD -> A panel L2-resident.
// ---------------------------------------------------------------------------
template<bool TANH, bool OUTBF, bool SUM>
__global__ __launch_bounds__(256) void gemm_bf16_kernel(
    const ushort_t* __restrict__ A, const ushort_t* __restrict__ BT,
    const float* __restrict__ bias, void* __restrict__ Cout,
    const float* __restrict__ addIn, ushort_t* __restrict__ sumOut,
    int M, int N, int K, int GX) {
    __shared__ __align__(16) ushort_t As[128 * 32];
    __shared__ __align__(16) ushort_t Bs[128 * 32];

    // XCD-chunk bijective swizzle (m204): XCD c (= launch id % 8) owns a
    // contiguous chunk of logical tile ids; consecutive logical ids share by.
    const int nwg = gridDim.x;
    const int orig = blockIdx.x;
    const int q = nwg >> 3, r = nwg & 7;
    const int xcd = orig & 7, slot = orig >> 3;
    const int wgid = (xcd < r ? xcd * (q + 1) : r * (q + 1) + (xcd - r) * q) + slot;
    const int bx = wgid % GX, by = wgid / GX;

    const int tid = threadIdx.x;
    const int wave = tid >> 6, lane = tid & 63;
    const int ln = lane & 15, quad = lane >> 4;
    const int wr = wave >> 1, wc = wave & 1;
    const int rowBase = by * 128;
    const int colBase = bx * 128;

    // staging: issue s covers chunk = s*256 + wave*64 + lane (16B chunks)
    const int c0 = wave * 64 + lane;
    const int r0 = c0 >> 2, ko0 = (c0 & 3) * 8;
    const int c1 = 256 + c0;
    const int r1 = c1 >> 2, ko1 = (c1 & 3) * 8;
    const ushort_t* gA0 = A + (size_t)(rowBase + r0) * K + ko0;
    const ushort_t* gA1 = A + (size_t)(rowBase + r1) * K + ko1;
    const ushort_t* gB0 = BT + (size_t)(colBase + r0) * K + ko0;
    const ushort_t* gB1 = BT + (size_t)(colBase + r1) * K + ko1;
    ushort_t* lA0 = As + wave * 512;          // wave-uniform LDS dest bases
    ushort_t* lA1 = As + 2048 + wave * 512;
    ushort_t* lB0 = Bs + wave * 512;
    ushort_t* lB1 = Bs + 2048 + wave * 512;

    f32x4 acc[4][4] = {};

    for (int k0 = 0; k0 < K; k0 += 32) {
        async_ld16(gA0 + k0, lA0);
        async_ld16(gA1 + k0, lA1);
        async_ld16(gB0 + k0, lB0);
        async_ld16(gB1 + k0, lB1);
        __syncthreads();

        bf16x8 a[4], b[4];
        #pragma unroll
        for (int i = 0; i < 4; ++i)
            a[i] = *(const bf16x8*)&As[(wr * 64 + i * 16 + ln) * 32 + quad * 8];
        #pragma unroll
        for (int j = 0; j < 4; ++j)
            b[j] = *(const bf16x8*)&Bs[(wc * 64 + j * 16 + ln) * 32 + quad * 8];
        #pragma unroll
        for (int i = 0; i < 4; ++i)
            #pragma unroll
            for (int j = 0; j < 4; ++j)
                acc[i][j] = __builtin_amdgcn_mfma_f32_16x16x32_bf16(a[i], b[j], acc[i][j], 0, 0, 0);
        __syncthreads();
    }

    // epilogue: C/D layout col=lane&15, row=quad*4+reg  [m89/m91 verified]
    float bv[4];
    #pragma unroll
    for (int j = 0; j < 4; ++j) bv[j] = bias[colBase + wc * 64 + j * 16 + ln];

    #pragma unroll
    for (int i = 0; i < 4; ++i) {
        #pragma unroll
        for (int rr = 0; rr < 4; ++rr) {
            const size_t row = (size_t)(rowBase + wr * 64 + i * 16 + quad * 4 + rr);
            #pragma unroll
            for (int j = 0; j < 4; ++j) {
                const int col = colBase + wc * 64 + j * 16 + ln;
                const size_t idx = row * (size_t)N + col;
                float v = acc[i][j][rr] + bv[j];
                if (TANH) v = tanhf(v);
                if (SUM) {
                    ((float*)Cout)[idx] = v;                 // raw fp32 (for softmax)
                    sumOut[idx] = f2bf(v + addIn[idx]);      // joint input, bf16
                } else if (OUTBF) {
                    ((ushort_t*)Cout)[idx] = f2bf(v);
                } else {
                    ((float*)Cout)[idx] = v;
                }
            }
        }
    }
}

// ---------------------------------------------------------------------------
// 6) In-place log-softmax, one WAVE per row of 1024 (shuffle-only, no LDS)
// ---------------------------------------------------------------------------
__global__ __launch_bounds__(256) void logsoftmax_kernel(float* __restrict__ x) {
    const int wave = threadIdx.x >> 6, lane = threadIdx.x & 63;
    const size_t base = ((size_t)blockIdx.x * 4 + wave) * VV;

    float4 v[4];
    #pragma unroll
    for (int i = 0; i < 4; ++i)
        v[i] = *(const float4*)&x[base + i * 256 + lane * 4];

    float m = fmaxf(fmaxf(v[0].x, v[0].y), fmaxf(v[0].z, v[0].w));
    #pragma unroll
    for (int i = 1; i < 4; ++i)
        m = fmaxf(m, fmaxf(fmaxf(v[i].x, v[i].y), fmaxf(v[i].z, v[i].w)));
    #pragma unroll
    for (int o = 1; o < 64; o <<= 1) m = fmaxf(m, __shfl_xor(m, o, 64));

    float s = 0.f;
    #pragma unroll
    for (int i = 0; i < 4; ++i)
        s += expf(v[i].x - m) + expf(v[i].y - m) + expf(v[i].z - m) + expf(v[i].w - m);
    #pragma unroll
    for (int o = 1; o < 64; o <<= 1) s += __shfl_xor(s, o, 64);

    const float lse = logf(s) + m;
    #pragma unroll
    for (int i = 0; i < 4; ++i) {
        v[i].x -= lse; v[i].y -= lse; v[i].z -= lse; v[i].w -= lse;
        *(float4*)&x[base + i * 256 + lane * 4] = v[i];
    }
}

// ---------------------------------------------------------------------------
// 7) enc_lens passthrough
// ---------------------------------------------------------------------------
__global__ void lens_kernel(const int* __restrict__ features_len,
                            float* __restrict__ out_lens) {
    if (threadIdx.x < BB) out_lens[threadIdx.x] = (float)features_len[threadIdx.x];
}

// ---------------------------------------------------------------------------
extern "C" void kernel_launch(void* const* d_in, const int* in_sizes, int n_in,
                              void* d_out, int out_size, void* d_ws, size_t ws_size,
                              hipStream_t stream) {
    const float* encoder_out  = (const float*)d_in[0];
    const int*   features_len = (const int*)  d_in[1];
    const int*   targets      = (const int*)  d_in[2];
    const float* W_enc = (const float*)d_in[3];
    const float* b_enc = (const float*)d_in[4];
    const float* emb   = (const float*)d_in[5];
    const float* W_p1  = (const float*)d_in[6];
    const float* b_p1  = (const float*)d_in[7];
    const float* W_p2  = (const float*)d_in[8];
    const float* b_p2  = (const float*)d_in[9];
    const float* W_po  = (const float*)d_in[10];
    const float* b_po  = (const float*)d_in[11];
    const float* W_j1  = (const float*)d_in[12];
    const float* b_j1  = (const float*)d_in[13];
    const float* W_j2  = (const float*)d_in[14];
    const float* b_j2  = (const float*)d_in[15];

    float* out = (float*)d_out;
    const size_t BTV = (size_t)MM * VV;
    float* out_logits = out;             // log_probs      [B,T,V]
    float* out_pred   = out + BTV;       // pred_log_probs [B,T,V]
    float* out_enc    = out + 2 * BTV;   // enc_log_probs  [B,T,V]
    float* out_lens   = out + 3 * BTV;   // enc_lens       [B]

    // ---- workspace layout (bytes), total 121,399,296 (same as before) ----
    // ctx | WT* | h1(41MB) | Abuf(32.7MB) | h2(41MB)
    // sumb aliases [h1|Abuf-head] (both dead when gemm4 writes it);
    // joint-hidden output goes to the h2 region (free after gemm4 reads it).
    char* ws = (char*)d_ws;
    int*      ctx0   = (int*)ws;                               // 128,000
    int*      ctx1   = (int*)(ws + 128000);                    // 128,000
    size_t off = 256000;
    ushort_t* WTenc = (ushort_t*)(ws + off); off += (size_t)VV * DENC * 2;  // 1,048,576
    ushort_t* WTp1  = (ushort_t*)(ws + off); off += (size_t)PP * DENC * 2;  //   655,360
    ushort_t* WTp2  = (ushort_t*)(ws + off); off += (size_t)PP * PP * 2;    //   819,200
    ushort_t* WTpo  = (ushort_t*)(ws + off); off += (size_t)VV * PP * 2;    // 1,310,720
    ushort_t* WTj1  = (ushort_t*)(ws + off); off += (size_t)PP * VV * 2;    // 1,310,720
    ushort_t* WTj2  = (ushort_t*)(ws + off); off += (size_t)VV * PP * 2;    // 1,310,720
    ushort_t* h1    = (ushort_t*)(ws + off);                                // 40,960,000
    ushort_t* Abuf  = (ushort_t*)(ws + off + (size_t)MM * PP * 2);          // 32,768,000
    ushort_t* h2    = (ushort_t*)(ws + off + (size_t)MM * PP * 2
                                          + (size_t)MM * DENC * 2);         // 40,960,000
    ushort_t* sumb  = h1;   // 65,536,000 (aliases h1 + head of Abuf)

    // 1) context
    ctx_kernel<<<BB, 256, 0, stream>>>(targets, ctx0, ctx1);

    // 2) weight transposes (fp32 -> bf16 [N,K])
    dim3 tcb(32, 8);
    transpose_cvt_kernel<<<dim3(VV/32, DENC/32), tcb, 0, stream>>>(W_enc, WTenc, DENC, VV);
    transpose_cvt_kernel<<<dim3(PP/32, DENC/32), tcb, 0, stream>>>(W_p1, WTp1, DENC, PP);
    transpose_cvt_kernel<<<dim3(PP/32, PP/32),   tcb, 0, stream>>>(W_p2, WTp2, PP, PP);
    transpose_cvt_kernel<<<dim3(VV/32, PP/32),   tcb, 0, stream>>>(W_po, WTpo, PP, VV);
    transpose_cvt_kernel<<<dim3(PP/32, VV/32),   tcb, 0, stream>>>(W_j1, WTj1, VV, PP);
    transpose_cvt_kernel<<<dim3(VV/32, PP/32),   tcb, 0, stream>>>(W_j2, WTj2, PP, VV);

    // 3) predictor input gather (bf16) -> Abuf, then predictor L1 -> h1
    gather_kernel<<<MM, 128, 0, stream>>>(emb, ctx0, ctx1, Abuf);
    gemm_bf16_kernel<true, true, false><<<(PP/128)*(MM/128), 256, 0, stream>>>(
        Abuf, WTp1, b_p1, h1, nullptr, nullptr, MM, PP, DENC, PP/128);

    // 4) encoder head: cvt encoder_out -> Abuf (free after gemm1), GEMM -> out_enc (fp32 raw)
    cvt_kernel<<<(MM * DENC / 4 + 255) / 256, 256, 0, stream>>>(encoder_out, Abuf, MM * DENC);
    gemm_bf16_kernel<false, false, false><<<(VV/128)*(MM/128), 256, 0, stream>>>(
        Abuf, WTenc, b_enc, out_enc, nullptr, nullptr, MM, VV, DENC, VV/128);

    // 5) predictor L2: h2 = tanh(h1 @ W_p2 + b_p2) (bf16)
    gemm_bf16_kernel<true, true, false><<<(PP/128)*(MM/128), 256, 0, stream>>>(
        h1, WTp2, b_p2, h2, nullptr, nullptr, MM, PP, PP, PP/128);

    // 6) predictor out + fused joint-input: out_pred = h2 @ W_po + b_po (fp32 raw),
    //    sumb = bf16(out_pred + out_enc)   [replaces separate add_cvt pass]
    gemm_bf16_kernel<false, false, true><<<(VV/128)*(MM/128), 256, 0, stream>>>(
        h2, WTpo, b_po, out_pred, out_enc, sumb, MM, VV, PP, VV/128);

    // 7) joint hidden: hj = tanh(sumb @ W_j1 + b_j1) -> h2 region (free now, bf16)
    gemm_bf16_kernel<true, true, false><<<(PP/128)*(MM/128), 256, 0, stream>>>(
        sumb, WTj1, b_j1, h2, nullptr, nullptr, MM, PP, VV, PP/128);

    // 8) joint out: logits = hj @ W_j2 + b_j2 -> out_logits (fp32 raw)
    gemm_bf16_kernel<false, false, false><<<(VV/128)*(MM/128), 256, 0, stream>>>(
        h2, WTj2, b_j2, out_logits, MM > 0 ? nullptr : nullptr, nullptr, MM, VV, PP, VV/128);

    // 9) in-place log_softmax over all three [32000,1024] sections (wave-per-row)
    logsoftmax_kernel<<<3 * MM / 4, 256, 0, stream>>>(out);

    // 10) enc_lens
    lens_kernel<<<1, 64, 0, stream>>>(features_len, out_lens);
}

// Round 2
// 969.544 us; speedup vs baseline: 1.0773x; 1.0309x over previous
//
#include <hip/hip_runtime.h>
#include <math.h>

typedef unsigned short ushort_t;
typedef unsigned int uint_t;

// Problem constants (fixed by the reference)
#define BB 16
#define TT 2000
#define DENC 512
#define VV 1024
#define EE 256
#define PP 640
#define MM (BB * TT)   // 32000 rows

// MFMA fragment types (per cdna_hip_programming.md §3, compile-verified on gfx950)
typedef __attribute__((ext_vector_type(8))) short bf16x8;
typedef __attribute__((ext_vector_type(4))) float f32x4;

// ---------------------------------------------------------------------------
// helpers
// ---------------------------------------------------------------------------
__device__ __forceinline__ ushort_t f2bf(float x) {
    union { float f; uint_t u; } v; v.f = x;
    uint_t r = v.u + 0x7fffu + ((v.u >> 16) & 1u);   // RTNE
    return (ushort_t)(r >> 16);
}

__device__ __forceinline__ void async_ld16(const ushort_t* g, ushort_t* l) {
    __builtin_amdgcn_global_load_lds(
        (const __attribute__((address_space(1))) void*)g,
        (__attribute__((address_space(3))) void*)l, 16, 0, 0);
}

// ---------------------------------------------------------------------------
// 1) Viterbi context
// ---------------------------------------------------------------------------
__global__ void ctx_kernel(const int* __restrict__ targets,
                           int* __restrict__ ctx0, int* __restrict__ ctx1) {
    __shared__ int tg[TT];
    __shared__ int cc[TT];
    const int b = blockIdx.x;
    const int* row = targets + b * TT;
    for (int t = threadIdx.x; t < TT; t += blockDim.x) tg[t] = row[t];
    __syncthreads();
    if (threadIdx.x == 0) {
        int cur = 0;
        for (int t = 0; t < TT; ++t) {
            cc[t] = cur;
            int v = tg[t];
            cur = (v != 0) ? v : cur;
        }
    }
    __syncthreads();
    for (int t = threadIdx.x; t < TT; t += blockDim.x) {
        ctx0[b * TT + t] = cc[t];
        ctx1[b * TT + t] = (t >= 1) ? cc[t - 1] : 0;
    }
}

// ---------------------------------------------------------------------------
// 2) Weight transpose + fp32->bf16: W[K,N] -> WT[N,K] (bf16)
// ---------------------------------------------------------------------------
__global__ __launch_bounds__(256) void transpose_cvt_kernel(
    const float* __restrict__ W, ushort_t* __restrict__ WT, int K, int N) {
    __shared__ float t[32][33];
    const int n0 = blockIdx.x * 32, k0 = blockIdx.y * 32;
    const int tx = threadIdx.x, ty0 = threadIdx.y;  // blockDim (32,8)
    #pragma unroll
    for (int i = 0; i < 4; ++i) {
        int ty = ty0 + i * 8;
        t[ty][tx] = W[(size_t)(k0 + ty) * N + n0 + tx];
    }
    __syncthreads();
    #pragma unroll
    for (int i = 0; i < 4; ++i) {
        int ty = ty0 + i * 8;
        WT[(size_t)(n0 + ty) * K + k0 + tx] = f2bf(t[tx][ty]);
    }
}

// ---------------------------------------------------------------------------
// 3) fp32 -> bf16 elementwise (n % 4 == 0)
// ---------------------------------------------------------------------------
__global__ __launch_bounds__(256) void cvt_kernel(const float* __restrict__ in,
                                                  ushort_t* __restrict__ out, int n) {
    int i = (blockIdx.x * 256 + threadIdx.x) * 4;
    if (i >= n) return;
    float4 v = *(const float4*)(in + i);
    ushort_t o[4] = {f2bf(v.x), f2bf(v.y), f2bf(v.z), f2bf(v.w)};
    *(uint2*)(out + i) = *(uint2*)o;
}

// ---------------------------------------------------------------------------
// 4) gather predictor input
// ---------------------------------------------------------------------------
__global__ __launch_bounds__(128) void gather_kernel(const float* __restrict__ emb,
                                                     const int* __restrict__ ctx0,
                                                     const int* __restrict__ ctx1,
                                                     ushort_t* __restrict__ out) {
    const int m = blockIdx.x;
    const int t = threadIdx.x;           // 0..127
    const int half = t >> 6;             // 0: ctx0, 1: ctx1
    const int c = half ? ctx1[m] : ctx0[m];
    const int e = (t & 63) * 4;
    float4 v = *(const float4*)&emb[(size_t)c * EE + e];
    ushort_t o[4] = {f2bf(v.x), f2bf(v.y), f2bf(v.z), f2bf(v.w)};
    *(uint2*)&out[(size_t)m * 512 + half * 256 + e] = *(uint2*)o;
}

// ---------------------------------------------------------------------------
// 5a) 128x128 m97-structure GEMM (kept for N=640 GEMMs)
// ---------------------------------------------------------------------------
template<bool TANH, bool OUTBF, bool SUM>
__global__ __launch_bounds__(256) void gemm_bf16_kernel(
    const ushort_t* __restrict__ A, const ushort_t* __restrict__ BT,
    const float* __restrict__ bias, void* __restrict__ Cout,
    const float* __restrict__ addIn, ushort_t* __restrict__ sumOut,
    int M, int N, int K, int GX) {
    __shared__ __align__(16) ushort_t As[128 * 32];
    __shared__ __align__(16) ushort_t Bs[128 * 32];

    const int nwg = gridDim.x;
    const int orig = blockIdx.x;
    const int q = nwg >> 3, r = nwg & 7;
    const int xcd = orig & 7, slot = orig >> 3;
    const int wgid = (xcd < r ? xcd * (q + 1) : r * (q + 1) + (xcd - r) * q) + slot;
    const int bx = wgid % GX, by = wgid / GX;

    const int tid = threadIdx.x;
    const int wave = tid >> 6, lane = tid & 63;
    const int ln = lane & 15, quad = lane >> 4;
    const int wr = wave >> 1, wc = wave & 1;
    const int rowBase = by * 128;
    const int colBase = bx * 128;

    const int c0 = wave * 64 + lane;
    const int r0 = c0 >> 2, ko0 = (c0 & 3) * 8;
    const int c1 = 256 + c0;
    const int r1 = c1 >> 2, ko1 = (c1 & 3) * 8;
    const ushort_t* gA0 = A + (size_t)(rowBase + r0) * K + ko0;
    const ushort_t* gA1 = A + (size_t)(rowBase + r1) * K + ko1;
    const ushort_t* gB0 = BT + (size_t)(colBase + r0) * K + ko0;
    const ushort_t* gB1 = BT + (size_t)(colBase + r1) * K + ko1;
    ushort_t* lA0 = As + wave * 512;
    ushort_t* lA1 = As + 2048 + wave * 512;
    ushort_t* lB0 = Bs + wave * 512;
    ushort_t* lB1 = Bs + 2048 + wave * 512;

    f32x4 acc[4][4] = {};

    for (int k0 = 0; k0 < K; k0 += 32) {
        async_ld16(gA0 + k0, lA0);
        async_ld16(gA1 + k0, lA1);
        async_ld16(gB0 + k0, lB0);
        async_ld16(gB1 + k0, lB1);
        __syncthreads();

        bf16x8 a[4], b[4];
        #pragma unroll
        for (int i = 0; i < 4; ++i)
            a[i] = *(const bf16x8*)&As[(wr * 64 + i * 16 + ln) * 32 + quad * 8];
        #pragma unroll
        for (int j = 0; j < 4; ++j)
            b[j] = *(const bf16x8*)&Bs[(wc * 64 + j * 16 + ln) * 32 + quad * 8];
        #pragma unroll
        for (int i = 0; i < 4; ++i)
            #pragma unroll
            for (int j = 0; j < 4; ++j)
                acc[i][j] = __builtin_amdgcn_mfma_f32_16x16x32_bf16(a[i], b[j], acc[i][j], 0, 0, 0);
        __syncthreads();
    }

    float bv[4];
    #pragma unroll
    for (int j = 0; j < 4; ++j) bv[j] = bias[colBase + wc * 64 + j * 16 + ln];

    #pragma unroll
    for (int i = 0; i < 4; ++i) {
        #pragma unroll
        for (int rr = 0; rr < 4; ++rr) {
            const size_t row = (size_t)(rowBase + wr * 64 + i * 16 + quad * 4 + rr);
            #pragma unroll
            for (int j = 0; j < 4; ++j) {
                const int col = colBase + wc * 64 + j * 16 + ln;
                const size_t idx = row * (size_t)N + col;
                float v = acc[i][j][rr] + bv[j];
                if (TANH) v = tanhf(v);
                if (SUM) {
                    ((float*)Cout)[idx] = v;
                    sumOut[idx] = f2bf(v + addIn[idx]);
                } else if (OUTBF) {
                    ((ushort_t*)Cout)[idx] = f2bf(v);
                } else {
                    ((float*)Cout)[idx] = v;
                }
            }
        }
    }
}

// ---------------------------------------------------------------------------
// 5b) 256x256 8-phase GEMM (T2+T3+T4+T5), fp32 out; optional fused SUM output.
//     A [M,K] bf16 rm, BT [N,K] bf16 rm. Requires M%256==0, N%256==0, K%64==0,
//     K >= 128. 512 threads = 8 waves (2M x 4N); per-wave out 128x64.
//     LDS 128 KiB: 2 bufs x (A[256][64] + B[256][64]) bf16, linear rows of
//     128 B with (row&7)<<4 byte-XOR swizzle (applied on global SOURCE for
//     global_load_lds and on ds_read addr - both-sides involution, rule #21).
//     Schedule per K-tile t (4 phases = 4 C-quadrants, 16 MFMA each):
//       ph0: read B-frags(8)+A-q0(4); stage A-half0(t+1) -> other buf
//       ph1: read A-q1;               stage A-half1(t+1) -> other buf
//       ph2: read A-q2;               stage B-half0(t+2) -> CUR buf (B read done ph0)
//       ph3: read A-q3;               stage B-half1(t+2) -> cur buf
//       each phase: barrier; setprio(1); MFMA x16; setprio(0); [ph3: vmcnt(4)]; barrier
//     vmcnt(4) = 2 loads/half x 2 half-tiles (B(t+2)) stay in flight - never 0.
// ---------------------------------------------------------------------------
__device__ __forceinline__ void stage_half(const ushort_t* __restrict__ X, int xBase,
                                           int K, int kt, int h, ushort_t* region,
                                           int tid) {
    const int wb = tid & ~63;  // wave*64 (wave-uniform part)
    #pragma unroll
    for (int s = 0; s < 2; ++s) {
        const int c  = s * 512 + tid;                 // chunk in half (0..1023)
        const int rH = c >> 3;                        // row in half (0..127)
        const int k8 = (c & 7) ^ (rH & 7);            // source pre-swizzle
        const ushort_t* g = X + (size_t)(xBase + h * 128 + rH) * K + kt + k8 * 8;
        ushort_t* l = region + ((size_t)(h * 1024 + s * 512 + wb)) * 8;  // linear dest
        async_ld16(g, l);
    }
}

template<bool SUM>
__global__ __launch_bounds__(512, 2) void gemm256_kernel(
    const ushort_t* __restrict__ A, const ushort_t* __restrict__ BT,
    const float* __restrict__ bias, float* __restrict__ Cout,
    const float* __restrict__ addIn, ushort_t* __restrict__ sumOut,
    int M, int N, int K, int GX) {
    extern __shared__ __align__(16) ushort_t sm[];   // 131072 bytes
    ushort_t* A0 = sm;                 // buf0 A [256][64] bf16 (16384 us)
    ushort_t* B0 = sm + 16384;         // buf0 B
    ushort_t* A1 = sm + 32768;         // buf1 A
    ushort_t* B1 = sm + 49152;         // buf1 B

    const int nwg = gridDim.x;
    const int orig = blockIdx.x;
    const int q8 = nwg >> 3, r8 = nwg & 7;
    const int xcd = orig & 7, slot = orig >> 3;
    const int wgid = (xcd < r8 ? xcd * (q8 + 1) : r8 * (q8 + 1) + (xcd - r8) * q8) + slot;
    const int bx = wgid % GX, by = wgid / GX;

    const int tid = threadIdx.x;        // 0..511
    const int lane = tid & 63;
    const int ln = lane & 15, quad = lane >> 4;
    const int wave = tid >> 6;
    const int wr = wave >> 2, wc = wave & 3;   // 2M x 4N waves
    const int rowBase = by * 256, colBase = bx * 256;
    const int NT = K >> 6;

    f32x4 acc[4][2][4] = {};   // [quadrant][m][n]

    // ---- prologue: tile0 full + tile1 B halves (12 loads/thread) ----
    stage_half(A,  rowBase, K, 0,  0, A0, tid);
    stage_half(A,  rowBase, K, 0,  1, A0, tid);
    stage_half(BT, colBase, K, 0,  0, B0, tid);
    stage_half(BT, colBase, K, 0,  1, B0, tid);
    stage_half(BT, colBase, K, 64, 0, B1, tid);
    stage_half(BT, colBase, K, 64, 1, B1, tid);
    asm volatile("s_waitcnt vmcnt(4)" ::: "memory");  // tile0 landed; B(1) in flight
    __builtin_amdgcn_s_barrier();

    for (int t = 0; t < NT; ++t) {
        const int cur = t & 1;
        const char* cA = (const char*)(cur ? A1 : A0);
        const char* cB = (const char*)(cur ? B1 : B0);
        ushort_t* oA = cur ? A0 : A1;          // A(t+1) dest
        ushort_t* cBw = cur ? B1 : B0;         // B(t+2) dest (cur B, consumed ph0)
        const int ktA = (t + 1 < NT ? t + 1 : NT - 1) * 64;
        const int ktB = (t + 2 < NT ? t + 2 : NT - 1) * 64;

        bf16x8 bfr[4][2];
        #pragma unroll
        for (int q = 0; q < 4; ++q) {
            if (q == 0) {
                #pragma unroll
                for (int n = 0; n < 4; ++n)
                    #pragma unroll
                    for (int ks = 0; ks < 2; ++ks) {
                        int off = (wc * 64 + n * 16 + ln) * 128 + ks * 64 + quad * 16;
                        off ^= (ln & 7) << 4;
                        bfr[n][ks] = *(const bf16x8*)(cB + off);
                    }
            }
            bf16x8 afr[2][2];
            #pragma unroll
            for (int m = 0; m < 2; ++m)
                #pragma unroll
                for (int ks = 0; ks < 2; ++ks) {
                    int off = (wr * 128 + q * 32 + m * 16 + ln) * 128 + ks * 64 + quad * 16;
                    off ^= (ln & 7) << 4;
                    afr[m][ks] = *(const bf16x8*)(cA + off);
                }
            if (q == 0)      stage_half(A,  rowBase, K, ktA, 0, oA, tid);
            else if (q == 1) stage_half(A,  rowBase, K, ktA, 1, oA, tid);
            else if (q == 2) stage_half(BT, colBase, K, ktB, 0, cBw, tid);
            else             stage_half(BT, colBase, K, ktB, 1, cBw, tid);

            __builtin_amdgcn_s_barrier();
            __builtin_amdgcn_s_setprio(1);
            #pragma unroll
            for (int m = 0; m < 2; ++m)
                #pragma unroll
                for (int n = 0; n < 4; ++n)
                    #pragma unroll
                    for (int ks = 0; ks < 2; ++ks)
                        acc[q][m][n] = __builtin_amdgcn_mfma_f32_16x16x32_bf16(
                            afr[m][ks], bfr[n][ks], acc[q][m][n], 0, 0, 0);
            __builtin_amdgcn_s_setprio(0);
            if (q == 3)
                asm volatile("s_waitcnt vmcnt(4)" ::: "memory");  // tile t+1 landed
            __builtin_amdgcn_s_barrier();
        }
    }

    // ---- epilogue ----
    float bv[4];
    #pragma unroll
    for (int n = 0; n < 4; ++n) bv[n] = bias[colBase + wc * 64 + n * 16 + ln];

    #pragma unroll
    for (int q = 0; q < 4; ++q)
        #pragma unroll
        for (int m = 0; m < 2; ++m)
            #pragma unroll
            for (int rr = 0; rr < 4; ++rr) {
                const size_t row = (size_t)(rowBase + wr * 128 + q * 32 + m * 16 + quad * 4 + rr);
                #pragma unroll
                for (int n = 0; n < 4; ++n) {
                    const int col = colBase + wc * 64 + n * 16 + ln;
                    const size_t idx = row * (size_t)N + col;
                    float v = acc[q][m][n][rr] + bv[n];
                    Cout[idx] = v;
                    if (SUM) sumOut[idx] = f2bf(v + addIn[idx]);
                }
            }
}

// ---------------------------------------------------------------------------
// 6) In-place log-softmax, one WAVE per row of 1024 (shuffle-only, no LDS)
// ---------------------------------------------------------------------------
__global__ __launch_bounds__(256) void logsoftmax_kernel(float* __restrict__ x) {
    const int wave = threadIdx.x >> 6, lane = threadIdx.x & 63;
    const size_t base = ((size_t)blockIdx.x * 4 + wave) * VV;

    float4 v[4];
    #pragma unroll
    for (int i = 0; i < 4; ++i)
        v[i] = *(const float4*)&x[base + i * 256 + lane * 4];

    float m = fmaxf(fmaxf(v[0].x, v[0].y), fmaxf(v[0].z, v[0].w));
    #pragma unroll
    for (int i = 1; i < 4; ++i)
        m = fmaxf(m, fmaxf(fmaxf(v[i].x, v[i].y), fmaxf(v[i].z, v[i].w)));
    #pragma unroll
    for (int o = 1; o < 64; o <<= 1) m = fmaxf(m, __shfl_xor(m, o, 64));

    float s = 0.f;
    #pragma unroll
    for (int i = 0; i < 4; ++i)
        s += expf(v[i].x - m) + expf(v[i].y - m) + expf(v[i].z - m) + expf(v[i].w - m);
    #pragma unroll
    for (int o = 1; o < 64; o <<= 1) s += __shfl_xor(s, o, 64);

    const float lse = logf(s) + m;
    #pragma unroll
    for (int i = 0; i < 4; ++i) {
        v[i].x -= lse; v[i].y -= lse; v[i].z -= lse; v[i].w -= lse;
        *(float4*)&x[base + i * 256 + lane * 4] = v[i];
    }
}

// ---------------------------------------------------------------------------
// 7) enc_lens passthrough
// ---------------------------------------------------------------------------
__global__ void lens_kernel(const int* __restrict__ features_len,
                            float* __restrict__ out_lens) {
    if (threadIdx.x < BB) out_lens[threadIdx.x] = (float)features_len[threadIdx.x];
}

// ---------------------------------------------------------------------------
extern "C" void kernel_launch(void* const* d_in, const int* in_sizes, int n_in,
                              void* d_out, int out_size, void* d_ws, size_t ws_size,
                              hipStream_t stream) {
    const float* encoder_out  = (const float*)d_in[0];
    const int*   features_len = (const int*)  d_in[1];
    const int*   targets      = (const int*)  d_in[2];
    const float* W_enc = (const float*)d_in[3];
    const float* b_enc = (const float*)d_in[4];
    const float* emb   = (const float*)d_in[5];
    const float* W_p1  = (const float*)d_in[6];
    const float* b_p1  = (const float*)d_in[7];
    const float* W_p2  = (const float*)d_in[8];
    const float* b_p2  = (const float*)d_in[9];
    const float* W_po  = (const float*)d_in[10];
    const float* b_po  = (const float*)d_in[11];
    const float* W_j1  = (const float*)d_in[12];
    const float* b_j1  = (const float*)d_in[13];
    const float* W_j2  = (const float*)d_in[14];
    const float* b_j2  = (const float*)d_in[15];

    float* out = (float*)d_out;
    const size_t BTV = (size_t)MM * VV;
    float* out_logits = out;             // log_probs      [B,T,V]
    float* out_pred   = out + BTV;       // pred_log_probs [B,T,V]
    float* out_enc    = out + 2 * BTV;   // enc_log_probs  [B,T,V]
    float* out_lens   = out + 3 * BTV;   // enc_lens       [B]

    // ---- workspace layout (bytes), total 121,399,296 (unchanged) ----
    char* ws = (char*)d_ws;
    int*      ctx0   = (int*)ws;                               // 128,000
    int*      ctx1   = (int*)(ws + 128000);                    // 128,000
    size_t off = 256000;
    ushort_t* WTenc = (ushort_t*)(ws + off); off += (size_t)VV * DENC * 2;  // 1,048,576
    ushort_t* WTp1  = (ushort_t*)(ws + off); off += (size_t)PP * DENC * 2;  //   655,360
    ushort_t* WTp2  = (ushort_t*)(ws + off); off += (size_t)PP * PP * 2;    //   819,200
    ushort_t* WTpo  = (ushort_t*)(ws + off); off += (size_t)VV * PP * 2;    // 1,310,720
    ushort_t* WTj1  = (ushort_t*)(ws + off); off += (size_t)PP * VV * 2;    // 1,310,720
    ushort_t* WTj2  = (ushort_t*)(ws + off); off += (size_t)VV * PP * 2;    // 1,310,720
    ushort_t* h1    = (ushort_t*)(ws + off);                                // 40,960,000
    ushort_t* Abuf  = (ushort_t*)(ws + off + (size_t)MM * PP * 2);          // 32,768,000
    ushort_t* h2    = (ushort_t*)(ws + off + (size_t)MM * PP * 2
                                          + (size_t)MM * DENC * 2);         // 40,960,000
    ushort_t* sumb  = h1;   // 65,536,000 (aliases h1 + head of Abuf)

    // allow 128 KiB dynamic LDS for the 256^2 kernels (host-side, graph-safe)
    hipFuncSetAttribute((const void*)&gemm256_kernel<false>,
                        hipFuncAttributeMaxDynamicSharedMemorySize, 131072);
    hipFuncSetAttribute((const void*)&gemm256_kernel<true>,
                        hipFuncAttributeMaxDynamicSharedMemorySize, 131072);

    // 1) context
    ctx_kernel<<<BB, 256, 0, stream>>>(targets, ctx0, ctx1);

    // 2) weight transposes (fp32 -> bf16 [N,K])
    dim3 tcb(32, 8);
    transpose_cvt_kernel<<<dim3(VV/32, DENC/32), tcb, 0, stream>>>(W_enc, WTenc, DENC, VV);
    transpose_cvt_kernel<<<dim3(PP/32, DENC/32), tcb, 0, stream>>>(W_p1, WTp1, DENC, PP);
    transpose_cvt_kernel<<<dim3(PP/32, PP/32),   tcb, 0, stream>>>(W_p2, WTp2, PP, PP);
    transpose_cvt_kernel<<<dim3(VV/32, PP/32),   tcb, 0, stream>>>(W_po, WTpo, PP, VV);
    transpose_cvt_kernel<<<dim3(PP/32, VV/32),   tcb, 0, stream>>>(W_j1, WTj1, VV, PP);
    transpose_cvt_kernel<<<dim3(VV/32, PP/32),   tcb, 0, stream>>>(W_j2, WTj2, PP, VV);

    // 3) predictor input gather (bf16) -> Abuf, then predictor L1 -> h1 (128^2 kernel)
    gather_kernel<<<MM, 128, 0, stream>>>(emb, ctx0, ctx1, Abuf);
    gemm_bf16_kernel<true, true, false><<<(PP/128)*(MM/128), 256, 0, stream>>>(
        Abuf, WTp1, b_p1, h1, nullptr, nullptr, MM, PP, DENC, PP/128);

    // 4) encoder head: cvt encoder_out -> Abuf (free), 256^2 GEMM -> out_enc (fp32)
    cvt_kernel<<<(MM * DENC / 4 + 255) / 256, 256, 0, stream>>>(encoder_out, Abuf, MM * DENC);
    gemm256_kernel<false><<<(VV/256)*(MM/256), 512, 131072, stream>>>(
        Abuf, WTenc, b_enc, out_enc, nullptr, nullptr, MM, VV, DENC, VV/256);

    // 5) predictor L2: h2 = tanh(h1 @ W_p2 + b_p2) (bf16, 128^2)
    gemm_bf16_kernel<true, true, false><<<(PP/128)*(MM/128), 256, 0, stream>>>(
        h1, WTp2, b_p2, h2, nullptr, nullptr, MM, PP, PP, PP/128);

    // 6) predictor out + fused joint-input (256^2 SUM):
    //    out_pred = h2 @ W_po + b_po (fp32), sumb = bf16(out_pred + out_enc)
    gemm256_kernel<true><<<(VV/256)*(MM/256), 512, 131072, stream>>>(
        h2, WTpo, b_po, out_pred, out_enc, sumb, MM, VV, PP, VV/256);

    // 7) joint hidden: hj = tanh(sumb @ W_j1 + b_j1) -> h2 region (128^2)
    gemm_bf16_kernel<true, true, false><<<(PP/128)*(MM/128), 256, 0, stream>>>(
        sumb, WTj1, b_j1, h2, nullptr, nullptr, MM, PP, VV, PP/128);

    // 8) joint out: logits = hj @ W_j2 + b_j2 -> out_logits (fp32, 256^2)
    gemm256_kernel<false><<<(VV/256)*(MM/256), 512, 131072, stream>>>(
        h2, WTj2, b_j2, out_logits, nullptr, nullptr, MM, VV, PP, VV/256);

    // 9) in-place log_softmax over all three [32000,1024] sections (wave-per-row)
    logsoftmax_kernel<<<3 * MM / 4, 256, 0, stream>>>(out);

    // 10) enc_lens
    lens_kernel<<<1, 64, 0, stream>>>(features_len, out_lens);
}

// Round 3
// 952.363 us; speedup vs baseline: 1.0967x; 1.0180x over previous
//
#include <hip/hip_runtime.h>
#include <math.h>

typedef unsigned short ushort_t;
typedef unsigned int uint_t;

// Problem constants (fixed by the reference)
#define BB 16
#define TT 2000
#define DENC 512
#define VV 1024
#define EE 256
#define PP 640
#define PPAD 768
#define MM (BB * TT)   // 32000 rows

typedef __attribute__((ext_vector_type(8))) short bf16x8;
typedef __attribute__((ext_vector_type(4))) float f32x4;

// ---------------------------------------------------------------------------
// helpers
// ---------------------------------------------------------------------------
__device__ __forceinline__ ushort_t f2bf(float x) {
    union { float f; uint_t u; } v; v.f = x;
    uint_t r = v.u + 0x7fffu + ((v.u >> 16) & 1u);   // RTNE
    return (ushort_t)(r >> 16);
}

__device__ __forceinline__ void async_ld16(const ushort_t* g, ushort_t* l) {
    __builtin_amdgcn_global_load_lds(
        (const __attribute__((address_space(1))) void*)g,
        (__attribute__((address_space(3))) void*)l, 16, 0, 0);
}

// ---------------------------------------------------------------------------
// 1) prep kernel: encoder cvt | 6 transposes | emb cvt | WT pad-zero |
//    padded biases + lens | parallel ctx scan.  One launch replaces 9.
// ---------------------------------------------------------------------------
#define NB_CVT  16000                    // MM*DENC/1024
#define B_TR    16000
#define NB_TR   3152
#define B_EMB   (B_TR + NB_TR)           // 19152
#define NB_EMB  256
#define B_PAD   (B_EMB + NB_EMB)         // 19408
#define NB_PAD  34
#define B_MISC  (B_PAD + NB_PAD)         // 19442
#define B_CTX   (B_MISC + 1)             // 19443
#define NB_PREP (B_CTX + BB)             // 19459

__global__ __launch_bounds__(256) void prep_kernel(
    const float* __restrict__ encoder_out, const int* __restrict__ features_len,
    const int* __restrict__ targets,
    const float* __restrict__ W_enc, const float* __restrict__ W_p1,
    const float* __restrict__ W_p2,  const float* __restrict__ W_po,
    const float* __restrict__ W_j1,  const float* __restrict__ W_j2,
    const float* __restrict__ b_p1,  const float* __restrict__ b_p2,
    const float* __restrict__ b_j1,  const float* __restrict__ emb,
    ushort_t* __restrict__ Abuf,
    ushort_t* __restrict__ WTenc, ushort_t* __restrict__ WTp1,
    ushort_t* __restrict__ WTp2,  ushort_t* __restrict__ WTpo,
    ushort_t* __restrict__ WTj1,  ushort_t* __restrict__ WTj2,
    ushort_t* __restrict__ embB,
    float* __restrict__ bp1p, float* __restrict__ bp2p, float* __restrict__ bj1p,
    int* __restrict__ ctx0, int* __restrict__ ctx1, float* __restrict__ out_lens) {
    const int blk = blockIdx.x;
    const int tid = threadIdx.x;

    if (blk < NB_CVT) {                       // encoder_out fp32 -> bf16 Abuf
        size_t i = ((size_t)blk * 256 + tid) * 4;
        float4 v = *(const float4*)(encoder_out + i);
        ushort_t o[4] = {f2bf(v.x), f2bf(v.y), f2bf(v.z), f2bf(v.w)};
        *(uint2*)(Abuf + i) = *(uint2*)o;
        return;
    }
    if (blk < B_EMB) {                        // weight transposes (real regions)
        int t = blk - B_TR;
        const float* W; ushort_t* WT; int K, N, base;
        if (t < 512)       { W = W_enc; WT = WTenc; K = 512;  N = 1024; base = 0; }
        else if (t < 832)  { W = W_p1;  WT = WTp1;  K = 512;  N = 640;  base = 512; }
        else if (t < 1232) { W = W_p2;  WT = WTp2;  K = 640;  N = 640;  base = 832; }
        else if (t < 1872) { W = W_po;  WT = WTpo;  K = 640;  N = 1024; base = 1232; }
        else if (t < 2512) { W = W_j1;  WT = WTj1;  K = 1024; N = 640;  base = 1872; }
        else               { W = W_j2;  WT = WTj2;  K = 640;  N = 1024; base = 2512; }
        t -= base;
        const int tilesN = N / 32;
        const int n0 = (t % tilesN) * 32, k0 = (t / tilesN) * 32;
        __shared__ float sm[32][33];
        const int tx = tid & 31, ty0 = tid >> 5;
        #pragma unroll
        for (int i = 0; i < 4; ++i) {
            int ty = ty0 + i * 8;
            sm[ty][tx] = W[(size_t)(k0 + ty) * N + n0 + tx];
        }
        __syncthreads();
        #pragma unroll
        for (int i = 0; i < 4; ++i) {
            int ty = ty0 + i * 8;
            WT[(size_t)(n0 + ty) * K + k0 + tx] = f2bf(sm[tx][ty]);
        }
        return;
    }
    if (blk < B_PAD) {                        // emb fp32 -> bf16 table (1024x256)
        int t = blk - B_EMB;
        size_t i = ((size_t)t * 256 + tid) * 4;
        float4 v = *(const float4*)(emb + i);
        ushort_t o[4] = {f2bf(v.x), f2bf(v.y), f2bf(v.z), f2bf(v.w)};
        *(uint2*)(embB + i) = *(uint2*)o;
        return;
    }
    if (blk < B_MISC) {                       // zero pad rows of padded WTs
        int t = blk - B_PAD;
        ushort_t* dst; size_t off;
        if (t < 8)       { dst = WTp1 + (size_t)640 * 512;  off = (size_t)t * 8192; }
        else if (t < 18) { dst = WTp2 + (size_t)640 * 640;  off = (size_t)(t - 8) * 8192; }
        else             { dst = WTj1 + (size_t)640 * 1024; off = (size_t)(t - 18) * 8192; }
        uint4 z = {0, 0, 0, 0};
        ushort_t* p = dst + off + tid * 32;
        #pragma unroll
        for (int i = 0; i < 4; ++i) *(uint4*)(p + i * 8) = z;
        return;
    }
    if (blk < B_CTX) {                        // padded biases + lens
        for (int t = tid; t < PPAD; t += 256) {
            bp1p[t] = (t < PP) ? b_p1[t] : 0.f;
            bp2p[t] = (t < PP) ? b_p2[t] : 0.f;
            bj1p[t] = (t < PP) ? b_j1[t] : 0.f;
        }
        if (tid < BB) out_lens[tid] = (float)features_len[tid];
        return;
    }
    {                                          // parallel ctx scan, one block/row
        const int b = blk - B_CTX;
        __shared__ int tg[2048];
        __shared__ int cc[2048];
        __shared__ int wl[4];
        const int* row = targets + b * TT;
        for (int t = tid; t < 2048; t += 256) tg[t] = (t < TT) ? row[t] : 0;
        __syncthreads();
        const int lane = tid & 63, wv = tid >> 6;
        const int base = tid * 8;
        int lastIdx = -1;                       // last non-blank abs idx in my chunk
        #pragma unroll
        for (int i = 0; i < 8; ++i) { if (tg[base + i] != 0) lastIdx = base + i; }
        int incl = lastIdx;                     // wave-inclusive max scan
        #pragma unroll
        for (int o = 1; o < 64; o <<= 1) {
            int u = __shfl_up(incl, o, 64);
            if (lane >= o) incl = max(incl, u);
        }
        if (lane == 63) wl[wv] = incl;
        __syncthreads();
        int excl = -1;
        for (int w = 0; w < 4; ++w) if (w < wv) excl = max(excl, wl[w]);
        int u = __shfl_up(incl, 1, 64);
        if (lane > 0) excl = max(excl, u);
        int cur = excl;                         // last non-blank idx strictly before my chunk
        #pragma unroll
        for (int i = 0; i < 8; ++i) {
            int idx = base + i;
            cc[idx] = (cur >= 0) ? tg[cur] : 0;
            if (tg[idx] != 0) cur = idx;
        }
        __syncthreads();
        for (int t = tid; t < TT; t += 256) {
            ctx0[b * TT + t] = cc[t];
            ctx1[b * TT + t] = t ? cc[t - 1] : 0;
        }
    }
}

// ---------------------------------------------------------------------------
// 2) 256x256 8-phase GEMM (T1+T2+T3+T4+T5), lda/ldc-parametrized.
//    OMODE 0: fp32 out; 1: bf16 tanh out; 2: fp32 out + bf16(out+addIn) sumOut.
//    GATHER: A row m = [embB[ctx0[m]] | embB[ctx1[m]]] (K=512), staged via
//    per-lane global_load_lds source addresses (LDS dest stays linear).
//    Swizzle: (row&7)<<4 byte-XOR, both-sides (pre-swizzled source + read XOR).
// ---------------------------------------------------------------------------
__device__ __forceinline__ void stage_half(const ushort_t* __restrict__ X, int xBase,
                                           int lda, int kt, int h, ushort_t* region,
                                           int tid) {
    const int wb = tid & ~63;
    #pragma unroll
    for (int s = 0; s < 2; ++s) {
        const int c  = s * 512 + tid;
        const int rH = c >> 3;
        const int k8 = (c & 7) ^ (rH & 7);
        const ushort_t* g = X + (size_t)(xBase + h * 128 + rH) * lda + kt + k8 * 8;
        ushort_t* l = region + ((size_t)(h * 1024 + s * 512 + wb)) * 8;
        async_ld16(g, l);
    }
}

__device__ __forceinline__ void stage_g(const ushort_t* b0, const ushort_t* b1,
                                        int kt, int h, int s, ushort_t* region, int tid) {
    const int wb = tid & ~63;
    const int c  = s * 512 + tid;
    const int rH = c >> 3;
    const int k8 = (c & 7) ^ (rH & 7);
    const ushort_t* base = (kt < 256) ? (b0 + kt) : (b1 + (kt - 256));
    async_ld16(base + k8 * 8, region + ((size_t)(h * 1024 + s * 512 + wb)) * 8);
}

template<int OMODE, bool GATHER>
__global__ __launch_bounds__(512, 2) void gemm256_kernel(
    const ushort_t* __restrict__ A, const ushort_t* __restrict__ BT,
    const float* __restrict__ bias, void* __restrict__ Cout,
    const float* __restrict__ addIn, ushort_t* __restrict__ sumOut,
    const ushort_t* __restrict__ embB, const int* __restrict__ ctx0,
    const int* __restrict__ ctx1,
    int N, int K, int lda, int ldc, int GX) {
    extern __shared__ __align__(16) ushort_t smem[];   // 131072 bytes
    ushort_t* A0 = smem;
    ushort_t* B0 = smem + 16384;
    ushort_t* A1 = smem + 32768;
    ushort_t* B1 = smem + 49152;

    const int nwg = gridDim.x;
    const int orig = blockIdx.x;
    const int q8 = nwg >> 3, r8 = nwg & 7;
    const int xcd = orig & 7, slot = orig >> 3;
    const int wgid = (xcd < r8 ? xcd * (q8 + 1) : r8 * (q8 + 1) + (xcd - r8) * q8) + slot;
    const int bx = wgid % GX, by = wgid / GX;

    const int tid = threadIdx.x;
    const int lane = tid & 63;
    const int ln = lane & 15, quad = lane >> 4;
    const int wave = tid >> 6;
    const int wr = wave >> 2, wc = wave & 3;
    const int rowBase = by * 256, colBase = bx * 256;
    const int NT = K >> 6;

    // GATHER: per-thread emb base pointers for its 4 staged rows
    const ushort_t* g0[2][2];
    const ushort_t* g1[2][2];
    if (GATHER) {
        #pragma unroll
        for (int h = 0; h < 2; ++h)
            #pragma unroll
            for (int s = 0; s < 2; ++s) {
                int rH = (s * 512 + tid) >> 3;
                int row = rowBase + h * 128 + rH;
                g0[h][s] = embB + (size_t)ctx0[row] * EE;
                g1[h][s] = embB + (size_t)ctx1[row] * EE;
            }
    }

    f32x4 acc[4][2][4] = {};

    // ---- prologue: tile0 A+B, tile1 B (12 loads/thread) ----
    if (GATHER) {
        stage_g(g0[0][0], g1[0][0], 0, 0, 0, A0, tid);
        stage_g(g0[0][1], g1[0][1], 0, 0, 1, A0, tid);
        stage_g(g0[1][0], g1[1][0], 0, 1, 0, A0, tid);
        stage_g(g0[1][1], g1[1][1], 0, 1, 1, A0, tid);
    } else {
        stage_half(A, rowBase, lda, 0, 0, A0, tid);
        stage_half(A, rowBase, lda, 0, 1, A0, tid);
    }
    stage_half(BT, colBase, K, 0,  0, B0, tid);
    stage_half(BT, colBase, K, 0,  1, B0, tid);
    stage_half(BT, colBase, K, 64, 0, B1, tid);
    stage_half(BT, colBase, K, 64, 1, B1, tid);
    asm volatile("s_waitcnt vmcnt(4)" ::: "memory");
    __builtin_amdgcn_s_barrier();

    for (int t = 0; t < NT; ++t) {
        const int cur = t & 1;
        const char* cA = (const char*)(cur ? A1 : A0);
        const char* cB = (const char*)(cur ? B1 : B0);
        ushort_t* oA  = cur ? A0 : A1;
        ushort_t* cBw = cur ? B1 : B0;
        const int ktA = (t + 1 < NT ? t + 1 : NT - 1) * 64;
        const int ktB = (t + 2 < NT ? t + 2 : NT - 1) * 64;

        bf16x8 bfr[4][2];
        #pragma unroll
        for (int q = 0; q < 4; ++q) {
            if (q == 0) {
                #pragma unroll
                for (int n = 0; n < 4; ++n)
                    #pragma unroll
                    for (int ks = 0; ks < 2; ++ks) {
                        int off = (wc * 64 + n * 16 + ln) * 128 + ks * 64 + quad * 16;
                        off ^= (ln & 7) << 4;
                        bfr[n][ks] = *(const bf16x8*)(cB + off);
                    }
            }
            bf16x8 afr[2][2];
            #pragma unroll
            for (int m = 0; m < 2; ++m)
                #pragma unroll
                for (int ks = 0; ks < 2; ++ks) {
                    int off = (wr * 128 + q * 32 + m * 16 + ln) * 128 + ks * 64 + quad * 16;
                    off ^= (ln & 7) << 4;
                    afr[m][ks] = *(const bf16x8*)(cA + off);
                }
            if (q == 0) {
                if (GATHER) { stage_g(g0[0][0], g1[0][0], ktA, 0, 0, oA, tid);
                              stage_g(g0[0][1], g1[0][1], ktA, 0, 1, oA, tid); }
                else        stage_half(A, rowBase, lda, ktA, 0, oA, tid);
            } else if (q == 1) {
                if (GATHER) { stage_g(g0[1][0], g1[1][0], ktA, 1, 0, oA, tid);
                              stage_g(g0[1][1], g1[1][1], ktA, 1, 1, oA, tid); }
                else        stage_half(A, rowBase, lda, ktA, 1, oA, tid);
            } else if (q == 2) {
                stage_half(BT, colBase, K, ktB, 0, cBw, tid);
            } else {
                stage_half(BT, colBase, K, ktB, 1, cBw, tid);
            }

            __builtin_amdgcn_s_barrier();
            __builtin_amdgcn_s_setprio(1);
            #pragma unroll
            for (int m = 0; m < 2; ++m)
                #pragma unroll
                for (int n = 0; n < 4; ++n)
                    #pragma unroll
                    for (int ks = 0; ks < 2; ++ks)
                        acc[q][m][n] = __builtin_amdgcn_mfma_f32_16x16x32_bf16(
                            afr[m][ks], bfr[n][ks], acc[q][m][n], 0, 0, 0);
            __builtin_amdgcn_s_setprio(0);
            if (q == 3)
                asm volatile("s_waitcnt vmcnt(4)" ::: "memory");
            __builtin_amdgcn_s_barrier();
        }
    }

    // ---- epilogue: C/D layout col=lane&15, row=quad*4+reg ----
    float bv[4];
    #pragma unroll
    for (int n = 0; n < 4; ++n) bv[n] = bias[colBase + wc * 64 + n * 16 + ln];

    #pragma unroll
    for (int q = 0; q < 4; ++q)
        #pragma unroll
        for (int m = 0; m < 2; ++m)
            #pragma unroll
            for (int rr = 0; rr < 4; ++rr) {
                const size_t row = (size_t)(rowBase + wr * 128 + q * 32 + m * 16 + quad * 4 + rr);
                #pragma unroll
                for (int n = 0; n < 4; ++n) {
                    const int col = colBase + wc * 64 + n * 16 + ln;
                    const size_t idx = row * (size_t)ldc + col;
                    float v = acc[q][m][n][rr] + bv[n];
                    if (OMODE == 0) {
                        ((float*)Cout)[idx] = v;
                    } else if (OMODE == 1) {
                        ((ushort_t*)Cout)[idx] = f2bf(tanhf(v));
                    } else {
                        ((float*)Cout)[idx] = v;
                        sumOut[idx] = f2bf(v + addIn[idx]);
                    }
                }
            }
}

// ---------------------------------------------------------------------------
// 3) In-place log-softmax, one WAVE per row of 1024 (shuffle-only, no LDS)
// ---------------------------------------------------------------------------
__global__ __launch_bounds__(256) void logsoftmax_kernel(float* __restrict__ x) {
    const int wave = threadIdx.x >> 6, lane = threadIdx.x & 63;
    const size_t base = ((size_t)blockIdx.x * 4 + wave) * VV;

    float4 v[4];
    #pragma unroll
    for (int i = 0; i < 4; ++i)
        v[i] = *(const float4*)&x[base + i * 256 + lane * 4];

    float m = fmaxf(fmaxf(v[0].x, v[0].y), fmaxf(v[0].z, v[0].w));
    #pragma unroll
    for (int i = 1; i < 4; ++i)
        m = fmaxf(m, fmaxf(fmaxf(v[i].x, v[i].y), fmaxf(v[i].z, v[i].w)));
    #pragma unroll
    for (int o = 1; o < 64; o <<= 1) m = fmaxf(m, __shfl_xor(m, o, 64));

    float s = 0.f;
    #pragma unroll
    for (int i = 0; i < 4; ++i)
        s += expf(v[i].x - m) + expf(v[i].y - m) + expf(v[i].z - m) + expf(v[i].w - m);
    #pragma unroll
    for (int o = 1; o < 64; o <<= 1) s += __shfl_xor(s, o, 64);

    const float lse = logf(s) + m;
    #pragma unroll
    for (int i = 0; i < 4; ++i) {
        v[i].x -= lse; v[i].y -= lse; v[i].z -= lse; v[i].w -= lse;
        *(float4*)&x[base + i * 256 + lane * 4] = v[i];
    }
}

// ---------------------------------------------------------------------------
extern "C" void kernel_launch(void* const* d_in, const int* in_sizes, int n_in,
                              void* d_out, int out_size, void* d_ws, size_t ws_size,
                              hipStream_t stream) {
    const float* encoder_out  = (const float*)d_in[0];
    const int*   features_len = (const int*)  d_in[1];
    const int*   targets      = (const int*)  d_in[2];
    const float* W_enc = (const float*)d_in[3];
    const float* b_enc = (const float*)d_in[4];
    const float* emb   = (const float*)d_in[5];
    const float* W_p1  = (const float*)d_in[6];
    const float* b_p1  = (const float*)d_in[7];
    const float* W_p2  = (const float*)d_in[8];
    const float* b_p2  = (const float*)d_in[9];
    const float* W_po  = (const float*)d_in[10];
    const float* b_po  = (const float*)d_in[11];
    const float* W_j1  = (const float*)d_in[12];
    const float* b_j1  = (const float*)d_in[13];
    const float* W_j2  = (const float*)d_in[14];
    const float* b_j2  = (const float*)d_in[15];

    float* out = (float*)d_out;
    const size_t BTV = (size_t)MM * VV;
    float* out_logits = out;             // log_probs      [B,T,V]
    float* out_pred   = out + BTV;       // pred_log_probs [B,T,V]
    float* out_enc    = out + 2 * BTV;   // enc_log_probs  [B,T,V]
    float* out_lens   = out + 3 * BTV;   // enc_lens       [B]

    // ---- workspace layout (bytes), total 138,873,856 ----
    char* ws = (char*)d_ws;
    int*      ctx0  = (int*)ws;                                             // 128,000
    int*      ctx1  = (int*)(ws + 128000);                                  // 128,000
    size_t off = 256000;
    ushort_t* embB  = (ushort_t*)(ws + off); off += (size_t)VV * EE * 2;    //   524,288
    ushort_t* WTenc = (ushort_t*)(ws + off); off += (size_t)VV * DENC * 2;  // 1,048,576
    ushort_t* WTp1  = (ushort_t*)(ws + off); off += (size_t)PPAD * DENC * 2;//   786,432
    ushort_t* WTp2  = (ushort_t*)(ws + off); off += (size_t)PPAD * PP * 2;  //   983,040
    ushort_t* WTpo  = (ushort_t*)(ws + off); off += (size_t)VV * PP * 2;    // 1,310,720
    ushort_t* WTj1  = (ushort_t*)(ws + off); off += (size_t)PPAD * VV * 2;  // 1,572,864
    ushort_t* WTj2  = (ushort_t*)(ws + off); off += (size_t)VV * PP * 2;    // 1,310,720
    float*    bp1p  = (float*)(ws + off); off += PPAD * 4;                  //     3,072
    float*    bp2p  = (float*)(ws + off); off += PPAD * 4;                  //     3,072
    float*    bj1p  = (float*)(ws + off); off += PPAD * 4;                  //     3,072
    ushort_t* h1    = (ushort_t*)(ws + off); off += (size_t)MM * PPAD * 2;  // 49,152,000
    ushort_t* Abuf  = (ushort_t*)(ws + off); off += (size_t)MM * DENC * 2;  // 32,768,000
    ushort_t* h2    = (ushort_t*)(ws + off);                                // 49,152,000
    ushort_t* sumb  = h1;   // 65,536,000; aliases h1 + head of Abuf (both dead)

    // allow 128 KiB dynamic LDS (host-side, graph-safe)
    hipFuncSetAttribute((const void*)&gemm256_kernel<1, true>,
                        hipFuncAttributeMaxDynamicSharedMemorySize, 131072);
    hipFuncSetAttribute((const void*)&gemm256_kernel<0, false>,
                        hipFuncAttributeMaxDynamicSharedMemorySize, 131072);
    hipFuncSetAttribute((const void*)&gemm256_kernel<1, false>,
                        hipFuncAttributeMaxDynamicSharedMemorySize, 131072);
    hipFuncSetAttribute((const void*)&gemm256_kernel<2, false>,
                        hipFuncAttributeMaxDynamicSharedMemorySize, 131072);

    // 1) prep: cvt + transposes + emb cvt + pads + biases + lens + ctx
    prep_kernel<<<NB_PREP, 256, 0, stream>>>(
        encoder_out, features_len, targets,
        W_enc, W_p1, W_p2, W_po, W_j1, W_j2,
        b_p1, b_p2, b_j1, emb,
        Abuf, WTenc, WTp1, WTp2, WTpo, WTj1, WTj2,
        embB, bp1p, bp2p, bj1p, ctx0, ctx1, out_lens);

    // 2) predictor L1 (gather fused): h1 = tanh(emb[ctx] @ W_p1 + b_p1), N=768 pad
    gemm256_kernel<1, true><<<(PPAD/256)*(MM/256), 512, 131072, stream>>>(
        nullptr, WTp1, bp1p, h1, nullptr, nullptr, embB, ctx0, ctx1,
        PPAD, DENC, 0, PPAD, PPAD/256);

    // 3) encoder head: out_enc = Abuf @ W_enc + b_enc (fp32)
    gemm256_kernel<0, false><<<(VV/256)*(MM/256), 512, 131072, stream>>>(
        Abuf, WTenc, b_enc, out_enc, nullptr, nullptr, nullptr, nullptr, nullptr,
        VV, DENC, DENC, VV, VV/256);

    // 4) predictor L2: h2 = tanh(h1 @ W_p2 + b_p2), K=640, lda=768, N=768 pad
    gemm256_kernel<1, false><<<(PPAD/256)*(MM/256), 512, 131072, stream>>>(
        h1, WTp2, bp2p, h2, nullptr, nullptr, nullptr, nullptr, nullptr,
        PPAD, PP, PPAD, PPAD, PPAD/256);

    // 5) predictor out + fused joint-input: out_pred = h2 @ W_po + b_po (fp32),
    //    sumb = bf16(out_pred + out_enc)
    gemm256_kernel<2, false><<<(VV/256)*(MM/256), 512, 131072, stream>>>(
        h2, WTpo, b_po, out_pred, out_enc, sumb, nullptr, nullptr, nullptr,
        VV, PP, PPAD, VV, VV/256);

    // 6) joint hidden: h2' = tanh(sumb @ W_j1 + b_j1), K=1024, N=768 pad
    gemm256_kernel<1, false><<<(PPAD/256)*(MM/256), 512, 131072, stream>>>(
        sumb, WTj1, bj1p, h2, nullptr, nullptr, nullptr, nullptr, nullptr,
        PPAD, VV, VV, PPAD, PPAD/256);

    // 7) joint out: logits = h2' @ W_j2 + b_j2 (fp32), K=640, lda=768
    gemm256_kernel<0, false><<<(VV/256)*(MM/256), 512, 131072, stream>>>(
        h2, WTj2, b_j2, out_logits, nullptr, nullptr, nullptr, nullptr, nullptr,
        VV, PP, PPAD, VV, VV/256);

    // 8) in-place log_softmax over all three [32000,1024] sections
    logsoftmax_kernel<<<3 * MM / 4, 256, 0, stream>>>(out);
}